// Round 1
// baseline (266.174 us; speedup 1.0000x reference)
//
#include <hip/hip_runtime.h>
#include <cstddef>

#define BDIM 4
#define CIN  256
#define CC   256
#define HH   64
#define WW   64
#define NG   4
#define GD   64
#define HWSZ (HH * WW)   // 4096

// ---------------- fused QKV 1x1-conv GEMM (fp32) ----------------
// per batch b: out[m, s] = sum_k W[m,k] * x[b,k,s] + bias[m], m in [0,768)
// BM=128 (out-ch tile), BN=128 (spatial tile), BK=8
#define BM 128
#define BN 128
#define BK 8

__global__ __launch_bounds__(256) void qkv_gemm_kernel(
    const float* __restrict__ x,
    const float* __restrict__ wq, const float* __restrict__ bq,
    const float* __restrict__ wk, const float* __restrict__ bk,
    const float* __restrict__ wv, const float* __restrict__ bv,
    float* __restrict__ qo, float* __restrict__ ko, float* __restrict__ vo)
{
    __shared__ float As[BK][BM + 4];
    __shared__ float Bs[BK][BN + 4];

    const int tid = threadIdx.x;
    const int bi  = blockIdx.x >> 5;            // 32 s-tiles per batch
    const int s0  = (blockIdx.x & 31) * BN;
    const int my  = blockIdx.y;                 // 0..5
    const int mat = my >> 1;                    // 0=q 1=k 2=v
    const int co0 = (my & 1) * BM;

    const float* wsel = (mat == 0) ? wq : (mat == 1) ? wk : wv;
    const float* bsel = (mat == 0) ? bq : (mat == 1) ? bk : bv;
    float*       osel = (mat == 0) ? qo : (mat == 1) ? ko : vo;

    const int ty = tid >> 4, tx = tid & 15;

    float acc[8][8];
    #pragma unroll
    for (int i = 0; i < 8; ++i) {
        const float bb = bsel[co0 + ty * 8 + i];
        #pragma unroll
        for (int j = 0; j < 8; ++j) acc[i][j] = bb;
    }

    const int a_co = tid >> 1;                  // 0..127
    const int a_k4 = (tid & 1) * 4;             // 0 or 4
    const int b_row = tid >> 5;                 // 0..7
    const int b_j4  = (tid & 31) * 4;           // 0..124

    const float* xb = x + (size_t)bi * CIN * HWSZ;

    for (int kt = 0; kt < CIN; kt += BK) {
        const float4 av  = *(const float4*)&wsel[(size_t)(co0 + a_co) * CIN + kt + a_k4];
        const float4 bvv = *(const float4*)&xb[(size_t)(kt + b_row) * HWSZ + s0 + b_j4];
        As[a_k4 + 0][a_co] = av.x;
        As[a_k4 + 1][a_co] = av.y;
        As[a_k4 + 2][a_co] = av.z;
        As[a_k4 + 3][a_co] = av.w;
        *(float4*)&Bs[b_row][b_j4] = bvv;
        __syncthreads();
        #pragma unroll
        for (int kk = 0; kk < BK; ++kk) {
            const float4 a0 = *(const float4*)&As[kk][ty * 8];
            const float4 a1 = *(const float4*)&As[kk][ty * 8 + 4];
            const float4 b0 = *(const float4*)&Bs[kk][tx * 8];
            const float4 b1 = *(const float4*)&Bs[kk][tx * 8 + 4];
            const float ar[8] = {a0.x, a0.y, a0.z, a0.w, a1.x, a1.y, a1.z, a1.w};
            const float br[8] = {b0.x, b0.y, b0.z, b0.w, b1.x, b1.y, b1.z, b1.w};
            #pragma unroll
            for (int i = 0; i < 8; ++i)
                #pragma unroll
                for (int j = 0; j < 8; ++j)
                    acc[i][j] += ar[i] * br[j];
        }
        __syncthreads();
    }

    float* ob = osel + (size_t)bi * CC * HWSZ;
    #pragma unroll
    for (int i = 0; i < 8; ++i) {
        const int row = co0 + ty * 8 + i;
        float* orow = ob + (size_t)row * HWSZ + s0 + tx * 8;
        *(float4*)&orow[0] = make_float4(acc[i][0], acc[i][1], acc[i][2], acc[i][3]);
        *(float4*)&orow[4] = make_float4(acc[i][4], acc[i][5], acc[i][6], acc[i][7]);
    }
}

// ---------------- local grouped attention (fp32) ----------------
// one thread per (b, g, h, w); block = 4 rows x 64 cols
__global__ __launch_bounds__(256) void loc_attn_kernel(
    const float* __restrict__ q, const float* __restrict__ k,
    const float* __restrict__ v, float* __restrict__ out)
{
    const int tid  = threadIdx.x;
    const int w    = tid & 63;
    const int hsub = tid >> 6;                  // 0..3
    const int ht   = blockIdx.x & 15;
    const int bg   = blockIdx.x >> 4;
    const int g    = bg & (NG - 1);
    const int bi   = bg >> 2;
    const int h    = ht * 4 + hsub;

    const size_t gbase = ((size_t)bi * CC + (size_t)g * GD) * HWSZ;
    const float* qg = q + gbase;
    const float* kg = k + gbase;
    const float* vg = v + gbase;
    const int off = h * WW + w;

    // preload this pixel's q row (64 channels) into registers
    float qr[GD];
    #pragma unroll
    for (int d = 0; d < GD; ++d) qr[d] = qg[(size_t)d * HWSZ + off];

    float logit[9];
    #pragma unroll
    for (int p = 0; p < 9; ++p) logit[p] = 0.f;

    // zero-padded unfold => OOB neighbors have k=0 -> logit stays 0 (and is
    // INCLUDED in the softmax), v=0 -> contributes nothing to output.
    #pragma unroll
    for (int p = 0; p < 9; ++p) {
        const int dh = p / 3 - 1, dw = p % 3 - 1;
        const int hh = h + dh, ww2 = w + dw;
        if (hh < 0 || hh >= HH || ww2 < 0 || ww2 >= WW) continue;
        const float* kp = kg + hh * WW + ww2;
        float acc = 0.f;
        #pragma unroll
        for (int d = 0; d < GD; ++d) acc += qr[d] * kp[(size_t)d * HWSZ];
        logit[p] = acc;
    }

    float mx = logit[0];
    #pragma unroll
    for (int p = 1; p < 9; ++p) mx = fmaxf(mx, logit[p]);
    float e[9];
    float s = 0.f;
    #pragma unroll
    for (int p = 0; p < 9; ++p) { e[p] = __expf(logit[p] - mx); s += e[p]; }
    const float inv = 1.f / s;
    float a[9];
    #pragma unroll
    for (int p = 0; p < 9; ++p) a[p] = e[p] * inv;

    float* ob = out + gbase + off;
    #pragma unroll 4
    for (int d = 0; d < GD; ++d) {
        float o = 0.f;
        #pragma unroll
        for (int p = 0; p < 9; ++p) {
            const int dh = p / 3 - 1, dw = p % 3 - 1;
            const int hh = h + dh, ww2 = w + dw;
            if (hh < 0 || hh >= HH || ww2 < 0 || ww2 >= WW) continue;
            o += a[p] * vg[(size_t)d * HWSZ + hh * WW + ww2];
        }
        ob[(size_t)d * HWSZ] = o;
    }
}

extern "C" void kernel_launch(void* const* d_in, const int* in_sizes, int n_in,
                              void* d_out, int out_size, void* d_ws, size_t ws_size,
                              hipStream_t stream) {
    const float* x  = (const float*)d_in[0];
    const float* wq = (const float*)d_in[1];
    const float* bq = (const float*)d_in[2];
    const float* wk = (const float*)d_in[3];
    const float* bk = (const float*)d_in[4];
    const float* wv = (const float*)d_in[5];
    const float* bv = (const float*)d_in[6];
    float* out = (float*)d_out;

    const size_t NTOT = (size_t)BDIM * CC * HWSZ;   // 4.19M floats each
    float* q = (float*)d_ws;
    float* k = q + NTOT;
    float* v = k + NTOT;

    dim3 gg(128, 6);
    qkv_gemm_kernel<<<gg, 256, 0, stream>>>(x, wq, bq, wk, bk, wv, bv, q, k, v);

    loc_attn_kernel<<<dim3(BDIM * NG * (HH / 4)), 256, 0, stream>>>(q, k, v, out);
}

// Round 2
// 116.075 us; speedup vs baseline: 2.2931x; 2.2931x over previous
//
#include <hip/hip_runtime.h>
#include <cstddef>

#define BDIM 4
#define CIN  256
#define CC   256
#define HH   64
#define WW   64
#define NG   4
#define GD   64
#define HWSZ (HH * WW)   // 4096

// ---------------- fused QKV 1x1-conv GEMM (fp32) ----------------
#define BM 128
#define BN 128
#define BK 8

__global__ __launch_bounds__(256) void qkv_gemm_kernel(
    const float* __restrict__ x,
    const float* __restrict__ wq, const float* __restrict__ bq,
    const float* __restrict__ wk, const float* __restrict__ bk,
    const float* __restrict__ wv, const float* __restrict__ bv,
    float* __restrict__ qo, float* __restrict__ ko, float* __restrict__ vo)
{
    __shared__ float As[BK][BM + 4];
    __shared__ float Bs[BK][BN + 4];

    const int tid = threadIdx.x;
    const int bi  = blockIdx.x >> 5;
    const int s0  = (blockIdx.x & 31) * BN;
    const int my  = blockIdx.y;
    const int mat = my >> 1;
    const int co0 = (my & 1) * BM;

    const float* wsel = (mat == 0) ? wq : (mat == 1) ? wk : wv;
    const float* bsel = (mat == 0) ? bq : (mat == 1) ? bk : bv;
    float*       osel = (mat == 0) ? qo : (mat == 1) ? ko : vo;

    const int ty = tid >> 4, tx = tid & 15;

    float acc[8][8];
    #pragma unroll
    for (int i = 0; i < 8; ++i) {
        const float bb = bsel[co0 + ty * 8 + i];
        #pragma unroll
        for (int j = 0; j < 8; ++j) acc[i][j] = bb;
    }

    const int a_co = tid >> 1;
    const int a_k4 = (tid & 1) * 4;
    const int b_row = tid >> 5;
    const int b_j4  = (tid & 31) * 4;

    const float* xb = x + (size_t)bi * CIN * HWSZ;

    for (int kt = 0; kt < CIN; kt += BK) {
        const float4 av  = *(const float4*)&wsel[(size_t)(co0 + a_co) * CIN + kt + a_k4];
        const float4 bvv = *(const float4*)&xb[(size_t)(kt + b_row) * HWSZ + s0 + b_j4];
        As[a_k4 + 0][a_co] = av.x;
        As[a_k4 + 1][a_co] = av.y;
        As[a_k4 + 2][a_co] = av.z;
        As[a_k4 + 3][a_co] = av.w;
        *(float4*)&Bs[b_row][b_j4] = bvv;
        __syncthreads();
        #pragma unroll
        for (int kk = 0; kk < BK; ++kk) {
            const float4 a0 = *(const float4*)&As[kk][ty * 8];
            const float4 a1 = *(const float4*)&As[kk][ty * 8 + 4];
            const float4 b0 = *(const float4*)&Bs[kk][tx * 8];
            const float4 b1 = *(const float4*)&Bs[kk][tx * 8 + 4];
            const float ar[8] = {a0.x, a0.y, a0.z, a0.w, a1.x, a1.y, a1.z, a1.w};
            const float br[8] = {b0.x, b0.y, b0.z, b0.w, b1.x, b1.y, b1.z, b1.w};
            #pragma unroll
            for (int i = 0; i < 8; ++i)
                #pragma unroll
                for (int j = 0; j < 8; ++j)
                    acc[i][j] += ar[i] * br[j];
        }
        __syncthreads();
    }

    float* ob = osel + (size_t)bi * CC * HWSZ;
    #pragma unroll
    for (int i = 0; i < 8; ++i) {
        const int row = co0 + ty * 8 + i;
        float* orow = ob + (size_t)row * HWSZ + s0 + tx * 8;
        *(float4*)&orow[0] = make_float4(acc[i][0], acc[i][1], acc[i][2], acc[i][3]);
        *(float4*)&orow[4] = make_float4(acc[i][4], acc[i][5], acc[i][6], acc[i][7]);
    }
}

// ---------------- local grouped attention (fp32, d-split x4) ----------------
// 4 threads per pixel, 16 channels each, packed in one wave at lane offsets
// {0,16,32,48}; logit reduction = 2x shfl_xor. Block = 256 thr covers one
// (b,g,h) full row of W=64. Grid = B*G*H = 1024 blocks.
#define DC 16   // channels per thread

__global__ __launch_bounds__(256) void loc_attn_kernel(
    const float* __restrict__ q, const float* __restrict__ k,
    const float* __restrict__ v, float* __restrict__ out)
{
    const int tid = threadIdx.x;
    const int wl  = tid & 15;                 // low lane bits -> w within wave
    const int c   = (tid >> 4) & 3;           // channel chunk 0..3
    const int wid = tid >> 6;                 // wave id 0..3
    const int w   = wid * 16 + wl;

    const int bx = blockIdx.x;
    const int h  = bx & (HH - 1);
    const int g  = (bx >> 6) & (NG - 1);
    const int bi = bx >> 8;

    const size_t gbase = ((size_t)bi * CC + (size_t)g * GD + (size_t)c * DC) * HWSZ;
    const float* qg = q + gbase;
    const float* kg = k + gbase;
    const float* vg = v + gbase;
    const int off = h * WW + w;

    float qr[DC];
    #pragma unroll
    for (int dd = 0; dd < DC; ++dd) qr[dd] = qg[(size_t)dd * HWSZ + off];

    // logits: partial dot over my 16 channels, then xor-reduce across the
    // 4 chunk-lanes (masks 16, 32). OOB neighbors -> logit 0 (zero-pad unfold).
    float logit[9];
    #pragma unroll
    for (int p = 0; p < 9; ++p) {
        const int dh = p / 3 - 1, dw = p % 3 - 1;
        const int hh = h + dh, ww2 = w + dw;
        float part = 0.f;
        if (hh >= 0 && hh < HH && ww2 >= 0 && ww2 < WW) {
            const float* kp = kg + hh * WW + ww2;
            #pragma unroll
            for (int dd = 0; dd < DC; ++dd) part += qr[dd] * kp[(size_t)dd * HWSZ];
        }
        part += __shfl_xor(part, 16, 64);
        part += __shfl_xor(part, 32, 64);
        logit[p] = part;
    }

    float mx = logit[0];
    #pragma unroll
    for (int p = 1; p < 9; ++p) mx = fmaxf(mx, logit[p]);
    float a[9];
    float s = 0.f;
    #pragma unroll
    for (int p = 0; p < 9; ++p) { a[p] = __expf(logit[p] - mx); s += a[p]; }
    const float inv = 1.f / s;
    #pragma unroll
    for (int p = 0; p < 9; ++p) a[p] *= inv;

    // PV over my 16 channels
    float acc[DC];
    #pragma unroll
    for (int dd = 0; dd < DC; ++dd) acc[dd] = 0.f;
    #pragma unroll
    for (int p = 0; p < 9; ++p) {
        const int dh = p / 3 - 1, dw = p % 3 - 1;
        const int hh = h + dh, ww2 = w + dw;
        if (hh < 0 || hh >= HH || ww2 < 0 || ww2 >= WW) continue;
        const float* vp = vg + hh * WW + ww2;
        const float ap = a[p];
        #pragma unroll
        for (int dd = 0; dd < DC; ++dd) acc[dd] += ap * vp[(size_t)dd * HWSZ];
    }

    float* ob = out + gbase + off;
    #pragma unroll
    for (int dd = 0; dd < DC; ++dd) ob[(size_t)dd * HWSZ] = acc[dd];
}

extern "C" void kernel_launch(void* const* d_in, const int* in_sizes, int n_in,
                              void* d_out, int out_size, void* d_ws, size_t ws_size,
                              hipStream_t stream) {
    const float* x  = (const float*)d_in[0];
    const float* wq = (const float*)d_in[1];
    const float* bq = (const float*)d_in[2];
    const float* wk = (const float*)d_in[3];
    const float* bk = (const float*)d_in[4];
    const float* wv = (const float*)d_in[5];
    const float* bv = (const float*)d_in[6];
    float* out = (float*)d_out;

    const size_t NTOT = (size_t)BDIM * CC * HWSZ;
    float* q = (float*)d_ws;
    float* k = q + NTOT;
    float* v = k + NTOT;

    dim3 gg(128, 6);
    qkv_gemm_kernel<<<gg, 256, 0, stream>>>(x, wq, bq, wk, bk, wv, bv, q, k, v);

    loc_attn_kernel<<<dim3(BDIM * NG * HH), 256, 0, stream>>>(q, k, v, out);
}

// Round 3
// 83.696 us; speedup vs baseline: 3.1802x; 1.3869x over previous
//
#include <hip/hip_runtime.h>
#include <cstddef>
#include <cstdint>

#define BDIM 4
#define HH   64
#define WW   64
#define NG   4
#define GD   64
#define HWSZ 4096
#define NTOT 16384          // BDIM*HWSZ
#define MDIM 768
#define XTC  512            // xt row: [hi(256) | lo(256)] bf16

typedef __attribute__((ext_vector_type(8))) short short8_t;
typedef __attribute__((ext_vector_type(4))) float f32x4;

__device__ __forceinline__ unsigned short bf16_rne(float x) {
    unsigned u = __float_as_uint(x);
    unsigned r = (u + 0x7fffu + ((u >> 16) & 1u)) >> 16;
    return (unsigned short)r;
}

__device__ __forceinline__ void lds_load16(const void* g, void* l) {
    __builtin_amdgcn_global_load_lds(
        (const __attribute__((address_space(1))) unsigned int*)g,
        (__attribute__((address_space(3))) unsigned int*)l, 16, 0, 0);
}

// ---------- prep: A' = [wh | wh | wl] (768x768 bf16) + fused bias ----------
__global__ __launch_bounds__(256) void prep_w_kernel(
    const float* __restrict__ wq, const float* __restrict__ bq,
    const float* __restrict__ wk, const float* __restrict__ bk,
    const float* __restrict__ wv, const float* __restrict__ bv,
    unsigned short* __restrict__ Ap, float* __restrict__ biasC)
{
    const int m = blockIdx.x;          // 0..767 (q:0-255, k:256-511, v:512-767)
    const int t = threadIdx.x;         // 0..255 (k index)
    const int mm = m & 255;
    const float* w = (m < 256) ? wq : (m < 512) ? wk : wv;
    const float x = w[(size_t)mm * 256 + t];
    const unsigned short h = bf16_rne(x);
    const float hf = __uint_as_float((unsigned)h << 16);
    const unsigned short lo = bf16_rne(x - hf);
    Ap[(size_t)m * MDIM + t]       = h;
    Ap[(size_t)m * MDIM + 256 + t] = h;
    Ap[(size_t)m * MDIM + 512 + t] = lo;
    if (t == 0) biasC[m] = (m < 256) ? bq[mm] : (m < 512) ? bk[mm] : bv[mm];
}

// ---------- transpose x[b][c][n] -> xt[b*4096+n][ hi(256) | lo(256) ] ----------
__global__ __launch_bounds__(256) void xpose_kernel(
    const float* __restrict__ x, unsigned short* __restrict__ xt)
{
    __shared__ float tile[64][65];
    const int t  = threadIdx.x;
    const int n0 = blockIdx.x * 64;
    const int c0 = blockIdx.y * 64;
    const int b  = blockIdx.z;

    const int tr = t >> 4, tc = (t & 15) * 4;
    #pragma unroll
    for (int i = 0; i < 4; ++i) {
        const int row = tr + i * 16;
        const float4 v = *(const float4*)&x[(size_t)(b * 256 + c0 + row) * HWSZ + n0 + tc];
        tile[row][tc + 0] = v.x; tile[row][tc + 1] = v.y;
        tile[row][tc + 2] = v.z; tile[row][tc + 3] = v.w;
    }
    __syncthreads();

    const int nr = t >> 2, cc = (t & 3) * 16;
    short8_t h0, h1, l0, l1;
    #pragma unroll
    for (int j = 0; j < 8; ++j) {
        float f = tile[cc + j][nr];
        unsigned short h = bf16_rne(f);
        h0[j] = (short)h;
        l0[j] = (short)bf16_rne(f - __uint_as_float((unsigned)h << 16));
    }
    #pragma unroll
    for (int j = 0; j < 8; ++j) {
        float f = tile[cc + 8 + j][nr];
        unsigned short h = bf16_rne(f);
        h1[j] = (short)h;
        l1[j] = (short)bf16_rne(f - __uint_as_float((unsigned)h << 16));
    }
    const size_t base = (size_t)(b * HWSZ + n0 + nr) * XTC + c0 + cc;
    *(short8_t*)&xt[base]           = h0;
    *(short8_t*)&xt[base + 8]       = h1;
    *(short8_t*)&xt[base + 256]     = l0;
    *(short8_t*)&xt[base + 256 + 8] = l1;
}

// ---------- QKV GEMM: D[m=768][n=16384] = A'[768x768] * B'[768 x n], bf16 MFMA ----------
// m97 structure: 128x128 tile, BK=32, 4 waves (2x2), global_load_lds w16.
// Output written TRANSPOSED: qkvt[n][m] fp32 (pixel-major for attn).
__global__ __launch_bounds__(256) void qkv_mfma_kernel(
    const unsigned short* __restrict__ Ap, const unsigned short* __restrict__ xt,
    const float* __restrict__ biasC, float* __restrict__ qkvt)
{
    __shared__ unsigned short As[128 * 32];   // [m][k] 8 KB
    __shared__ unsigned short Bs[128 * 32];   // [n][k] 8 KB

    const int t  = threadIdx.x;
    const int bx = blockIdx.x;
    const int u  = (bx & 7) * 96 + (bx >> 3);   // XCD-chunked (768 = 8*96)
    const int mt = u % 6;
    const int nt = u / 6;                       // 0..127

    const int l    = t & 63;
    const int wid  = t >> 6;
    const int wm   = wid >> 1, wn = wid & 1;
    const int lrow = l & 15;
    const int lk   = (l >> 4) * 8;
    const int lrow4 = (l >> 4) * 4;

    f32x4 acc[4][4];
    #pragma unroll
    for (int mi = 0; mi < 4; ++mi) {
        const f32x4 bb = *(const f32x4*)&biasC[mt * 128 + wm * 64 + mi * 16 + lrow4];
        #pragma unroll
        for (int ni = 0; ni < 4; ++ni) acc[mi][ni] = bb;
    }

    // staging: 2 issues of 4KB per operand; thread t covers 16B at linear off t*16
    const int e  = t * 8;            // element offset within 4KB half (shorts)
    const int r0 = e >> 5;           // row 0..63
    const int kc = e & 31;
    const unsigned short* agp0 = Ap + (size_t)(mt * 128 + r0) * MDIM + kc;
    const unsigned short* agp1 = Ap + (size_t)(mt * 128 + 64 + r0) * MDIM + kc;
    const unsigned short* bgp0 = xt + (size_t)(nt * 128 + r0) * XTC + kc;
    const unsigned short* bgp1 = xt + (size_t)(nt * 128 + 64 + r0) * XTC + kc;

    for (int kt = 0; kt < 24; ++kt) {
        const int ka = kt * 32;                               // A' col base
        const int kb = (kt < 16) ? kt * 32 : (kt - 16) * 32;  // xt col base (hi reused)
        lds_load16(agp0 + ka, As + t * 8);
        lds_load16(agp1 + ka, As + 2048 + t * 8);
        lds_load16(bgp0 + kb, Bs + t * 8);
        lds_load16(bgp1 + kb, Bs + 2048 + t * 8);
        __syncthreads();

        short8_t a[4], bf[4];
        #pragma unroll
        for (int mi = 0; mi < 4; ++mi)
            a[mi] = *(const short8_t*)&As[(wm * 64 + mi * 16 + lrow) * 32 + lk];
        #pragma unroll
        for (int ni = 0; ni < 4; ++ni)
            bf[ni] = *(const short8_t*)&Bs[(wn * 64 + ni * 16 + lrow) * 32 + lk];
        #pragma unroll
        for (int mi = 0; mi < 4; ++mi)
            #pragma unroll
            for (int ni = 0; ni < 4; ++ni)
                acc[mi][ni] = __builtin_amdgcn_mfma_f32_16x16x32_bf16(
                    a[mi], bf[ni], acc[mi][ni], 0, 0, 0);
        __syncthreads();
    }

    // epilogue: D[row=m][col=n], row = (l>>4)*4+reg, col = l&15 -> qkvt[n][m]
    #pragma unroll
    for (int ni = 0; ni < 4; ++ni) {
        const size_t ng = (size_t)(nt * 128 + wn * 64 + ni * 16 + lrow);
        #pragma unroll
        for (int mi = 0; mi < 4; ++mi) {
            const int mg = mt * 128 + wm * 64 + mi * 16 + lrow4;
            *(f32x4*)&qkvt[ng * MDIM + mg] = acc[mi][ni];
        }
    }
}

// ---------- local grouped attention, pixel-major qkvt ----------
#define DC 16
__global__ __launch_bounds__(256) void loc_attn_kernel(
    const float* __restrict__ qkvt, float* __restrict__ out)
{
    const int t   = threadIdx.x;
    const int bx0 = blockIdx.x;
    const int bx  = (bx0 & 7) * 128 + (bx0 >> 3);   // 1024 = 8*128, h-contiguous per XCD
    const int h = bx & 63;
    const int g = (bx >> 6) & 3;
    const int b = bx >> 8;

    const int wl  = t & 15;
    const int c   = (t >> 4) & 3;
    const int wid = t >> 6;
    const int w   = wid * 16 + wl;

    const int colq = g * 64 + c * 16;
    const size_t rowq = (size_t)(b * HWSZ + h * 64 + w) * MDIM + colq;

    float4 q[4];
    #pragma unroll
    for (int j = 0; j < 4; ++j) q[j] = *(const float4*)&qkvt[rowq + j * 4];

    float logit[9];
    #pragma unroll
    for (int p = 0; p < 9; ++p) {
        const int dh = p / 3 - 1, dw = p % 3 - 1;
        const int hh = h + dh, ww2 = w + dw;
        float part = 0.f;
        if (hh >= 0 && hh < HH && ww2 >= 0 && ww2 < WW) {
            const float* kp = &qkvt[(size_t)(b * HWSZ + hh * 64 + ww2) * MDIM + 256 + colq];
            #pragma unroll
            for (int j = 0; j < 4; ++j) {
                const float4 kv = *(const float4*)&kp[j * 4];
                part += q[j].x * kv.x + q[j].y * kv.y + q[j].z * kv.z + q[j].w * kv.w;
            }
        }
        part += __shfl_xor(part, 16, 64);
        part += __shfl_xor(part, 32, 64);
        logit[p] = part;
    }

    float mx = logit[0];
    #pragma unroll
    for (int p = 1; p < 9; ++p) mx = fmaxf(mx, logit[p]);
    float a[9];
    float s = 0.f;
    #pragma unroll
    for (int p = 0; p < 9; ++p) { a[p] = __expf(logit[p] - mx); s += a[p]; }
    const float inv = 1.f / s;
    #pragma unroll
    for (int p = 0; p < 9; ++p) a[p] *= inv;

    float acc[DC];
    #pragma unroll
    for (int dd = 0; dd < DC; ++dd) acc[dd] = 0.f;
    #pragma unroll
    for (int p = 0; p < 9; ++p) {
        const int dh = p / 3 - 1, dw = p % 3 - 1;
        const int hh = h + dh, ww2 = w + dw;
        if (hh < 0 || hh >= HH || ww2 < 0 || ww2 >= WW) continue;
        const float* vp = &qkvt[(size_t)(b * HWSZ + hh * 64 + ww2) * MDIM + 512 + colq];
        const float ap = a[p];
        #pragma unroll
        for (int j = 0; j < 4; ++j) {
            const float4 vv = *(const float4*)&vp[j * 4];
            acc[j * 4 + 0] += ap * vv.x;
            acc[j * 4 + 1] += ap * vv.y;
            acc[j * 4 + 2] += ap * vv.z;
            acc[j * 4 + 3] += ap * vv.w;
        }
    }

    const int obase = b * 256 + colq;
    const int off = h * 64 + w;
    #pragma unroll
    for (int dd = 0; dd < DC; ++dd)
        out[(size_t)(obase + dd) * HWSZ + off] = acc[dd];
}

extern "C" void kernel_launch(void* const* d_in, const int* in_sizes, int n_in,
                              void* d_out, int out_size, void* d_ws, size_t ws_size,
                              hipStream_t stream) {
    const float* x  = (const float*)d_in[0];
    const float* wq = (const float*)d_in[1];
    const float* bq = (const float*)d_in[2];
    const float* wk = (const float*)d_in[3];
    const float* bk = (const float*)d_in[4];
    const float* wv = (const float*)d_in[5];
    const float* bv = (const float*)d_in[6];
    float* out = (float*)d_out;

    char* ws = (char*)d_ws;
    float*          qkvt  = (float*)ws;                         // 16384*768*4  = 50331648 B
    unsigned short* xt    = (unsigned short*)(ws + 50331648);   // 16384*512*2  = 16777216 B
    unsigned short* Ap    = (unsigned short*)(ws + 67108864);   // 768*768*2    =  1179648 B
    float*          biasC = (float*)(ws + 68288512);            // 768*4        =     3072 B

    prep_w_kernel<<<dim3(768), 256, 0, stream>>>(wq, bq, wk, bk, wv, bv, Ap, biasC);
    xpose_kernel<<<dim3(64, 4, 4), 256, 0, stream>>>(x, xt);
    qkv_mfma_kernel<<<dim3(768), 256, 0, stream>>>(Ap, xt, biasC, qkvt);
    loc_attn_kernel<<<dim3(1024), 256, 0, stream>>>(qkvt, out);
}

// Round 5
// 63.898 us; speedup vs baseline: 4.1656x; 1.3098x over previous
//
#include <hip/hip_runtime.h>
#include <cstddef>
#include <cstdint>

#define BDIM 4
#define HH   64
#define WW   64
#define NG   4
#define GD   64
#define HWSZ 4096
#define NTOT 16384          // BDIM*HWSZ
#define MDIM 768
#define XTC  512            // xt row: [hi(256) | lo(256)] bf16

typedef __attribute__((ext_vector_type(8))) short short8_t;
typedef __attribute__((ext_vector_type(4))) short short4_t;
typedef __attribute__((ext_vector_type(4))) float f32x4;

__device__ __forceinline__ unsigned short bf16_rne(float x) {
    unsigned u = __float_as_uint(x);
    unsigned r = (u + 0x7fffu + ((u >> 16) & 1u)) >> 16;
    return (unsigned short)r;
}

__device__ __forceinline__ float bf16_to_f32(short s) {
    return __uint_as_float(((unsigned)(unsigned short)s) << 16);
}

__device__ __forceinline__ void lds_load16(const void* g, void* l) {
    __builtin_amdgcn_global_load_lds(
        (const __attribute__((address_space(1))) unsigned int*)g,
        (__attribute__((address_space(3))) unsigned int*)l, 16, 0, 0);
}

// ---------- prep: A' = [Wh | Wh | Wl] (768x768 bf16) + bias ----------
__global__ __launch_bounds__(256) void prep_w_kernel(
    const float* __restrict__ wq, const float* __restrict__ bq,
    const float* __restrict__ wk, const float* __restrict__ bk,
    const float* __restrict__ wv, const float* __restrict__ bv,
    unsigned short* __restrict__ Ap, float* __restrict__ biasC)
{
    const int m = blockIdx.x;          // 0..767 (q:0-255, k:256-511, v:512-767)
    const int t = threadIdx.x;         // 0..255 (cin index)
    const int mm = m & 255;
    const float* w = (m < 256) ? wq : (m < 512) ? wk : wv;
    const float x = w[(size_t)mm * 256 + t];
    const unsigned short h = bf16_rne(x);
    const float hf = __uint_as_float((unsigned)h << 16);
    const unsigned short lo = bf16_rne(x - hf);
    Ap[(size_t)m * MDIM + t]       = h;
    Ap[(size_t)m * MDIM + 256 + t] = h;
    Ap[(size_t)m * MDIM + 512 + t] = lo;
    if (t == 0) biasC[m] = (m < 256) ? bq[mm] : (m < 512) ? bk[mm] : bv[mm];
}

// ---------- transpose x[b][c][n] -> xt[b*4096+n][ hi(256) | lo(256) ] ----------
__global__ __launch_bounds__(256) void xpose_kernel(
    const float* __restrict__ x, unsigned short* __restrict__ xt)
{
    __shared__ float tile[64][65];
    const int t  = threadIdx.x;
    const int n0 = blockIdx.x * 64;
    const int c0 = blockIdx.y * 64;
    const int b  = blockIdx.z;

    const int tr = t >> 4, tc = (t & 15) * 4;
    #pragma unroll
    for (int i = 0; i < 4; ++i) {
        const int row = tr + i * 16;
        const float4 v = *(const float4*)&x[(size_t)(b * 256 + c0 + row) * HWSZ + n0 + tc];
        tile[row][tc + 0] = v.x; tile[row][tc + 1] = v.y;
        tile[row][tc + 2] = v.z; tile[row][tc + 3] = v.w;
    }
    __syncthreads();

    const int nr = t >> 2, cc = (t & 3) * 16;
    short8_t h0, h1, l0, l1;
    #pragma unroll
    for (int j = 0; j < 8; ++j) {
        float f = tile[cc + j][nr];
        unsigned short h = bf16_rne(f);
        h0[j] = (short)h;
        l0[j] = (short)bf16_rne(f - __uint_as_float((unsigned)h << 16));
    }
    #pragma unroll
    for (int j = 0; j < 8; ++j) {
        float f = tile[cc + 8 + j][nr];
        unsigned short h = bf16_rne(f);
        h1[j] = (short)h;
        l1[j] = (short)bf16_rne(f - __uint_as_float((unsigned)h << 16));
    }
    const size_t base = (size_t)(b * HWSZ + n0 + nr) * XTC + c0 + cc;
    *(short8_t*)&xt[base]           = h0;
    *(short8_t*)&xt[base + 8]       = h1;
    *(short8_t*)&xt[base + 256]     = l0;
    *(short8_t*)&xt[base + 256 + 8] = l1;
}

// ---------- QKV GEMM: [768 x 768] * [768 x 16384] bf16 MFMA ----------
// 128x128 tile, BK=32, 4 waves, global_load_lds w16. Blocked outputs:
// q,k -> fp32 [m/16][n][16]; v -> bf16 [m/16][n][16]
__global__ __launch_bounds__(256) void qkv_mfma_kernel(
    const unsigned short* __restrict__ Ap, const unsigned short* __restrict__ xt,
    const float* __restrict__ biasC, float* __restrict__ qb,
    float* __restrict__ kb, unsigned short* __restrict__ vb)
{
    __shared__ unsigned short As[128 * 32];   // 8 KB
    __shared__ unsigned short Bs[128 * 32];   // 8 KB

    const int t  = threadIdx.x;
    const int bx = blockIdx.x;
    const int u  = (bx & 7) * 96 + (bx >> 3);   // XCD-chunked (768 = 8*96)
    const int mt = u % 6;
    const int nt = u / 6;                       // 0..127

    const int l     = t & 63;
    const int wid   = t >> 6;
    const int wm    = wid >> 1, wn = wid & 1;
    const int lrow  = l & 15;
    const int lk    = (l >> 4) * 8;
    const int lrow4 = (l >> 4) * 4;

    f32x4 acc[4][4];
    #pragma unroll
    for (int mi = 0; mi < 4; ++mi) {
        const f32x4 bb = *(const f32x4*)&biasC[mt * 128 + wm * 64 + mi * 16 + lrow4];
        #pragma unroll
        for (int ni = 0; ni < 4; ++ni) acc[mi][ni] = bb;
    }

    const int e  = t * 8;            // shorts within a 4KB half (64 rows x 32k)
    const int r0 = e >> 5;           // row 0..63
    const int kc = e & 31;
    const unsigned short* agp0 = Ap + (size_t)(mt * 128 + r0) * MDIM + kc;
    const unsigned short* agp1 = Ap + (size_t)(mt * 128 + 64 + r0) * MDIM + kc;
    const unsigned short* bgp0 = xt + (size_t)(nt * 128 + r0) * XTC + kc;
    const unsigned short* bgp1 = xt + (size_t)(nt * 128 + 64 + r0) * XTC + kc;

    for (int kt = 0; kt < 24; ++kt) {
        const int ka = kt * 32;                               // A' col
        const int kb2 = (kt < 16) ? kt * 32 : (kt - 16) * 32; // xt col (hi reused)
        lds_load16(agp0 + ka, As + t * 8);
        lds_load16(agp1 + ka, As + 2048 + t * 8);
        lds_load16(bgp0 + kb2, Bs + t * 8);
        lds_load16(bgp1 + kb2, Bs + 2048 + t * 8);
        __syncthreads();

        short8_t a[4], bf[4];
        #pragma unroll
        for (int mi = 0; mi < 4; ++mi)
            a[mi] = *(const short8_t*)&As[(wm * 64 + mi * 16 + lrow) * 32 + lk];
        #pragma unroll
        for (int ni = 0; ni < 4; ++ni)
            bf[ni] = *(const short8_t*)&Bs[(wn * 64 + ni * 16 + lrow) * 32 + lk];
        #pragma unroll
        for (int mi = 0; mi < 4; ++mi)
            #pragma unroll
            for (int ni = 0; ni < 4; ++ni)
                acc[mi][ni] = __builtin_amdgcn_mfma_f32_16x16x32_bf16(
                    a[mi], bf[ni], acc[mi][ni], 0, 0, 0);
        __syncthreads();
    }

    // epilogue: D row (m) = (l>>4)*4+reg, col (n) = l&15 — blocked stores
    #pragma unroll
    for (int ni = 0; ni < 4; ++ni) {
        const size_t ng = (size_t)(nt * 128 + wn * 64 + ni * 16 + lrow);
        if (mt < 2) {                 // q: fp32
            #pragma unroll
            for (int mi = 0; mi < 4; ++mi) {
                const int chunk = mt * 8 + wm * 4 + mi;          // 0..15
                *(f32x4*)&qb[((size_t)chunk * NTOT + ng) * 16 + lrow4] = acc[mi][ni];
            }
        } else if (mt < 4) {          // k: fp32
            #pragma unroll
            for (int mi = 0; mi < 4; ++mi) {
                const int chunk = (mt - 2) * 8 + wm * 4 + mi;    // 0..15
                *(f32x4*)&kb[((size_t)chunk * NTOT + ng) * 16 + lrow4] = acc[mi][ni];
            }
        } else {                      // v: bf16
            #pragma unroll
            for (int mi = 0; mi < 4; ++mi) {
                const int chunk = (mt - 4) * 8 + wm * 4 + mi;    // 0..15
                short4_t hs;
                #pragma unroll
                for (int j = 0; j < 4; ++j) hs[j] = (short)bf16_rne(acc[mi][ni][j]);
                *(short4_t*)&vb[((size_t)chunk * NTOT + ng) * 16 + lrow4] = hs;
            }
        }
    }
}

// ---------- local grouped attention: q,k fp32 blocked; v bf16 blocked ----------
__global__ __launch_bounds__(256) void loc_attn_kernel(
    const float* __restrict__ qb, const float* __restrict__ kb,
    const unsigned short* __restrict__ vb, float* __restrict__ out)
{
    const int t   = threadIdx.x;
    const int bx0 = blockIdx.x;
    const int bx  = (bx0 & 7) * 128 + (bx0 >> 3);
    const int h = bx & 63;
    const int g = (bx >> 6) & 3;
    const int b = bx >> 8;

    const int wl  = t & 15;
    const int c   = (t >> 4) & 3;
    const int wid = t >> 6;
    const int w   = wid * 16 + wl;

    const int ck = g * 4 + c;                    // chunk index 0..15
    const size_t n = (size_t)b * HWSZ + h * 64 + w;

    float4 q[4];
    #pragma unroll
    for (int j = 0; j < 4; ++j)
        q[j] = *(const float4*)&qb[((size_t)ck * NTOT + n) * 16 + j * 4];

    float logit[9];
    #pragma unroll
    for (int p = 0; p < 9; ++p) {
        const int dh = p / 3 - 1, dw = p % 3 - 1;
        const int hh = h + dh, ww2 = w + dw;
        float part = 0.f;
        if (hh >= 0 && hh < HH && ww2 >= 0 && ww2 < WW) {
            const size_t nn = (size_t)b * HWSZ + hh * 64 + ww2;
            const float* kp = &kb[((size_t)ck * NTOT + nn) * 16];
            #pragma unroll
            for (int j = 0; j < 4; ++j) {
                const float4 kv = *(const float4*)&kp[j * 4];
                part += q[j].x * kv.x + q[j].y * kv.y + q[j].z * kv.z + q[j].w * kv.w;
            }
        }
        part += __shfl_xor(part, 16, 64);
        part += __shfl_xor(part, 32, 64);
        logit[p] = part;
    }

    float mx = logit[0];
    #pragma unroll
    for (int p = 1; p < 9; ++p) mx = fmaxf(mx, logit[p]);
    float a[9];
    float s = 0.f;
    #pragma unroll
    for (int p = 0; p < 9; ++p) { a[p] = __expf(logit[p] - mx); s += a[p]; }
    const float inv = 1.f / s;
    #pragma unroll
    for (int p = 0; p < 9; ++p) a[p] *= inv;

    float acc[16];
    #pragma unroll
    for (int dd = 0; dd < 16; ++dd) acc[dd] = 0.f;
    #pragma unroll
    for (int p = 0; p < 9; ++p) {
        const int dh = p / 3 - 1, dw = p % 3 - 1;
        const int hh = h + dh, ww2 = w + dw;
        if (hh < 0 || hh >= HH || ww2 < 0 || ww2 >= WW) continue;
        const size_t nn = (size_t)b * HWSZ + hh * 64 + ww2;
        const unsigned short* vp = &vb[((size_t)ck * NTOT + nn) * 16];
        const short8_t v0 = *(const short8_t*)&vp[0];
        const short8_t v1 = *(const short8_t*)&vp[8];
        const float ap = a[p];
        #pragma unroll
        for (int j = 0; j < 8; ++j) acc[j]     += ap * bf16_to_f32(v0[j]);
        #pragma unroll
        for (int j = 0; j < 8; ++j) acc[8 + j] += ap * bf16_to_f32(v1[j]);
    }

    const int obase = b * 256 + g * 64 + c * 16;
    const int off = h * 64 + w;
    #pragma unroll
    for (int dd = 0; dd < 16; ++dd)
        out[(size_t)(obase + dd) * HWSZ + off] = acc[dd];
}

extern "C" void kernel_launch(void* const* d_in, const int* in_sizes, int n_in,
                              void* d_out, int out_size, void* d_ws, size_t ws_size,
                              hipStream_t stream) {
    const float* x  = (const float*)d_in[0];
    const float* wq = (const float*)d_in[1];
    const float* bq = (const float*)d_in[2];
    const float* wk = (const float*)d_in[3];
    const float* bk = (const float*)d_in[4];
    const float* wv = (const float*)d_in[5];
    const float* bv = (const float*)d_in[6];
    float* out = (float*)d_out;

    char* ws = (char*)d_ws;
    float*          qb    = (float*)ws;                         // 16.78 MB
    float*          kb    = (float*)(ws + 16777216);            // 16.78 MB
    unsigned short* vb    = (unsigned short*)(ws + 33554432);   //  8.39 MB
    unsigned short* xt    = (unsigned short*)(ws + 41943040);   // 16.78 MB
    unsigned short* Ap    = (unsigned short*)(ws + 58720256);   //  1.18 MB
    float*          biasC = (float*)(ws + 59899904);            //  3 KB

    prep_w_kernel<<<dim3(768), 256, 0, stream>>>(wq, bq, wk, bk, wv, bv, Ap, biasC);
    xpose_kernel<<<dim3(64, 4, 4), 256, 0, stream>>>(x, xt);
    qkv_mfma_kernel<<<dim3(768), 256, 0, stream>>>(Ap, xt, biasC, qb, kb, vb);
    loc_attn_kernel<<<dim3(1024), 256, 0, stream>>>(qb, kb, vb, out);
}

// Round 6
// 51.204 us; speedup vs baseline: 5.1983x; 1.2479x over previous
//
#include <hip/hip_runtime.h>
#include <cstddef>
#include <cstdint>

#define BDIM 4
#define HH   64
#define WW   64
#define NG   4
#define GD   64
#define HWSZ 4096
#define NTOT 16384          // BDIM*HWSZ
#define MDIM 768
#define XTC  512            // xt row: [hi(256) | lo(256)] bf16

typedef __attribute__((ext_vector_type(8))) short short8_t;
typedef __attribute__((ext_vector_type(4))) float f32x4;
typedef _Float16 f16x4_t __attribute__((ext_vector_type(4)));
typedef _Float16 f16x8_t __attribute__((ext_vector_type(8)));

__device__ __forceinline__ unsigned short bf16_rne(float x) {
    unsigned u = __float_as_uint(x);
    unsigned r = (u + 0x7fffu + ((u >> 16) & 1u)) >> 16;
    return (unsigned short)r;
}

__device__ __forceinline__ void lds_load16(const void* g, void* l) {
    __builtin_amdgcn_global_load_lds(
        (const __attribute__((address_space(1))) unsigned int*)g,
        (__attribute__((address_space(3))) unsigned int*)l, 16, 0, 0);
}

// ---------- fused prep: blocks 0..1023 transpose x, 1024..1791 build A'+bias ----------
// A' = [Wh | Wh | Wl] (768x768 bf16); xt[n][ hi(256) | lo(256) ]
__global__ __launch_bounds__(256) void prep_kernel(
    const float* __restrict__ x,
    const float* __restrict__ wq, const float* __restrict__ bq,
    const float* __restrict__ wk, const float* __restrict__ bk,
    const float* __restrict__ wv, const float* __restrict__ bv,
    unsigned short* __restrict__ xt, unsigned short* __restrict__ Ap,
    float* __restrict__ biasC)
{
    __shared__ float tile[64][65];
    const int t = threadIdx.x;
    const int bx = blockIdx.x;

    if (bx < 1024) {
        const int n0 = (bx & 63) * 64;
        const int c0 = ((bx >> 6) & 3) * 64;
        const int b  = bx >> 8;

        const int tr = t >> 4, tc = (t & 15) * 4;
        #pragma unroll
        for (int i = 0; i < 4; ++i) {
            const int row = tr + i * 16;
            const float4 v = *(const float4*)&x[(size_t)(b * 256 + c0 + row) * HWSZ + n0 + tc];
            tile[row][tc + 0] = v.x; tile[row][tc + 1] = v.y;
            tile[row][tc + 2] = v.z; tile[row][tc + 3] = v.w;
        }
        __syncthreads();

        const int nr = t >> 2, cc = (t & 3) * 16;
        short8_t h0, h1, l0, l1;
        #pragma unroll
        for (int j = 0; j < 8; ++j) {
            float f = tile[cc + j][nr];
            unsigned short h = bf16_rne(f);
            h0[j] = (short)h;
            l0[j] = (short)bf16_rne(f - __uint_as_float((unsigned)h << 16));
        }
        #pragma unroll
        for (int j = 0; j < 8; ++j) {
            float f = tile[cc + 8 + j][nr];
            unsigned short h = bf16_rne(f);
            h1[j] = (short)h;
            l1[j] = (short)bf16_rne(f - __uint_as_float((unsigned)h << 16));
        }
        const size_t base = (size_t)(b * HWSZ + n0 + nr) * XTC + c0 + cc;
        *(short8_t*)&xt[base]           = h0;
        *(short8_t*)&xt[base + 8]       = h1;
        *(short8_t*)&xt[base + 256]     = l0;
        *(short8_t*)&xt[base + 256 + 8] = l1;
    } else {
        const int m  = bx - 1024;          // 0..767
        const int mm = m & 255;
        const float* w = (m < 256) ? wq : (m < 512) ? wk : wv;
        const float xv = w[(size_t)mm * 256 + t];
        const unsigned short h = bf16_rne(xv);
        const float hf = __uint_as_float((unsigned)h << 16);
        const unsigned short lo = bf16_rne(xv - hf);
        Ap[(size_t)m * MDIM + t]       = h;
        Ap[(size_t)m * MDIM + 256 + t] = h;
        Ap[(size_t)m * MDIM + 512 + t] = lo;
        if (t == 0) biasC[m] = (m < 256) ? bq[mm] : (m < 512) ? bk[mm] : bv[mm];
    }
}

// ---------- QKV GEMM: [768 x 768] * [768 x 16384] bf16 MFMA, BK=64 ----------
// 128x128 tile, 4 waves, global_load_lds w16. Blocked fp16 outputs:
// qh,kh,vh -> [m/16][n][16] _Float16
__global__ __launch_bounds__(256) void qkv_mfma_kernel(
    const unsigned short* __restrict__ Ap, const unsigned short* __restrict__ xt,
    const float* __restrict__ biasC, _Float16* __restrict__ qh,
    _Float16* __restrict__ kh, _Float16* __restrict__ vh)
{
    __shared__ unsigned short As[128 * 64];   // 16 KB
    __shared__ unsigned short Bs[128 * 64];   // 16 KB

    const int t  = threadIdx.x;
    const int bx = blockIdx.x;
    const int u  = (bx & 7) * 96 + (bx >> 3);   // XCD-chunked (768 = 8*96)
    const int mt = u % 6;
    const int nt = u / 6;                       // 0..127

    const int l     = t & 63;
    const int wid   = t >> 6;
    const int wm    = wid >> 1, wn = wid & 1;
    const int lrow  = l & 15;
    const int lk    = (l >> 4) * 8;
    const int lrow4 = (l >> 4) * 4;

    f32x4 acc[4][4];
    #pragma unroll
    for (int mi = 0; mi < 4; ++mi) {
        const f32x4 bb = *(const f32x4*)&biasC[mt * 128 + wm * 64 + mi * 16 + lrow4];
        #pragma unroll
        for (int ni = 0; ni < 4; ++ni) acc[mi][ni] = bb;
    }

    // staging: per step 4 issues/operand; thread covers 16B at t*16 within each 4KB quarter
    const int rq = t >> 3;            // 0..31 row within quarter
    const int kc = (t & 7) * 8;       // 0..56 shorts
    const unsigned short* agp[4];
    const unsigned short* bgp[4];
    #pragma unroll
    for (int i = 0; i < 4; ++i) {
        agp[i] = Ap + (size_t)(mt * 128 + i * 32 + rq) * MDIM + kc;
        bgp[i] = xt + (size_t)(nt * 128 + i * 32 + rq) * XTC + kc;
    }

    for (int kt = 0; kt < 12; ++kt) {
        const int ka  = kt * 64;                        // A' col
        const int kb2 = (kt < 8 ? kt : kt - 8) * 64;    // xt col (hi | lo | hi)
        #pragma unroll
        for (int i = 0; i < 4; ++i) {
            lds_load16(agp[i] + ka,  As + i * 2048 + t * 8);
            lds_load16(bgp[i] + kb2, Bs + i * 2048 + t * 8);
        }
        __syncthreads();

        #pragma unroll
        for (int kk = 0; kk < 64; kk += 32) {
            short8_t a[4], bf[4];
            #pragma unroll
            for (int mi = 0; mi < 4; ++mi)
                a[mi] = *(const short8_t*)&As[(wm * 64 + mi * 16 + lrow) * 64 + kk + lk];
            #pragma unroll
            for (int ni = 0; ni < 4; ++ni)
                bf[ni] = *(const short8_t*)&Bs[(wn * 64 + ni * 16 + lrow) * 64 + kk + lk];
            #pragma unroll
            for (int mi = 0; mi < 4; ++mi)
                #pragma unroll
                for (int ni = 0; ni < 4; ++ni)
                    acc[mi][ni] = __builtin_amdgcn_mfma_f32_16x16x32_bf16(
                        a[mi], bf[ni], acc[mi][ni], 0, 0, 0);
        }
        __syncthreads();
    }

    // epilogue: D row (m) = (l>>4)*4+reg, col (n) = l&15 — blocked fp16 stores
    #pragma unroll
    for (int ni = 0; ni < 4; ++ni) {
        const size_t ng = (size_t)(nt * 128 + wn * 64 + ni * 16 + lrow);
        #pragma unroll
        for (int mi = 0; mi < 4; ++mi) {
            f16x4_t hv;
            #pragma unroll
            for (int j = 0; j < 4; ++j) hv[j] = (_Float16)acc[mi][ni][j];
            const int c8 = wm * 4 + mi;                  // 0..7 within this mt
            if (mt < 2)
                *(f16x4_t*)&qh[((size_t)(mt * 8 + c8) * NTOT + ng) * 16 + lrow4] = hv;
            else if (mt < 4)
                *(f16x4_t*)&kh[((size_t)((mt - 2) * 8 + c8) * NTOT + ng) * 16 + lrow4] = hv;
            else
                *(f16x4_t*)&vh[((size_t)((mt - 4) * 8 + c8) * NTOT + ng) * 16 + lrow4] = hv;
        }
    }
}

// ---------- local grouped attention: q,k,v fp16 blocked; fp32 math ----------
__global__ __launch_bounds__(256) void loc_attn_kernel(
    const _Float16* __restrict__ qh, const _Float16* __restrict__ kh,
    const _Float16* __restrict__ vh, float* __restrict__ out)
{
    const int t   = threadIdx.x;
    const int bx0 = blockIdx.x;
    const int bx  = (bx0 & 7) * 128 + (bx0 >> 3);
    const int h = bx & 63;
    const int g = (bx >> 6) & 3;
    const int b = bx >> 8;

    const int wl  = t & 15;
    const int c   = (t >> 4) & 3;
    const int wid = t >> 6;
    const int w   = wid * 16 + wl;

    const int ck = g * 4 + c;                    // chunk index 0..15
    const size_t n = (size_t)b * HWSZ + h * 64 + w;

    float qf[16];
    {
        const _Float16* qp = &qh[((size_t)ck * NTOT + n) * 16];
        const f16x8_t q0 = *(const f16x8_t*)qp;
        const f16x8_t q1 = *(const f16x8_t*)(qp + 8);
        #pragma unroll
        for (int j = 0; j < 8; ++j) { qf[j] = (float)q0[j]; qf[8 + j] = (float)q1[j]; }
    }

    float logit[9];
    #pragma unroll
    for (int p = 0; p < 9; ++p) {
        const int dh = p / 3 - 1, dw = p % 3 - 1;
        const int hh = h + dh, ww2 = w + dw;
        float part = 0.f;
        if (hh >= 0 && hh < HH && ww2 >= 0 && ww2 < WW) {
            const size_t nn = (size_t)b * HWSZ + hh * 64 + ww2;
            const _Float16* kp = &kh[((size_t)ck * NTOT + nn) * 16];
            const f16x8_t k0 = *(const f16x8_t*)kp;
            const f16x8_t k1 = *(const f16x8_t*)(kp + 8);
            #pragma unroll
            for (int j = 0; j < 8; ++j)
                part += qf[j] * (float)k0[j] + qf[8 + j] * (float)k1[j];
        }
        part += __shfl_xor(part, 16, 64);
        part += __shfl_xor(part, 32, 64);
        logit[p] = part;
    }

    float mx = logit[0];
    #pragma unroll
    for (int p = 1; p < 9; ++p) mx = fmaxf(mx, logit[p]);
    float a[9];
    float s = 0.f;
    #pragma unroll
    for (int p = 0; p < 9; ++p) { a[p] = __expf(logit[p] - mx); s += a[p]; }
    const float inv = 1.f / s;
    #pragma unroll
    for (int p = 0; p < 9; ++p) a[p] *= inv;

    float acc[16];
    #pragma unroll
    for (int dd = 0; dd < 16; ++dd) acc[dd] = 0.f;
    #pragma unroll
    for (int p = 0; p < 9; ++p) {
        const int dh = p / 3 - 1, dw = p % 3 - 1;
        const int hh = h + dh, ww2 = w + dw;
        if (hh < 0 || hh >= HH || ww2 < 0 || ww2 >= WW) continue;
        const size_t nn = (size_t)b * HWSZ + hh * 64 + ww2;
        const _Float16* vp = &vh[((size_t)ck * NTOT + nn) * 16];
        const f16x8_t v0 = *(const f16x8_t*)vp;
        const f16x8_t v1 = *(const f16x8_t*)(vp + 8);
        const float ap = a[p];
        #pragma unroll
        for (int j = 0; j < 8; ++j) {
            acc[j]     += ap * (float)v0[j];
            acc[8 + j] += ap * (float)v1[j];
        }
    }

    const int obase = b * 256 + g * 64 + c * 16;
    const int off = h * 64 + w;
    #pragma unroll
    for (int dd = 0; dd < 16; ++dd)
        out[(size_t)(obase + dd) * HWSZ + off] = acc[dd];
}

extern "C" void kernel_launch(void* const* d_in, const int* in_sizes, int n_in,
                              void* d_out, int out_size, void* d_ws, size_t ws_size,
                              hipStream_t stream) {
    const float* x  = (const float*)d_in[0];
    const float* wq = (const float*)d_in[1];
    const float* bq = (const float*)d_in[2];
    const float* wk = (const float*)d_in[3];
    const float* bk = (const float*)d_in[4];
    const float* wv = (const float*)d_in[5];
    const float* bv = (const float*)d_in[6];
    float* out = (float*)d_out;

    char* ws = (char*)d_ws;
    _Float16*       qh    = (_Float16*)ws;                      //  8.39 MB
    _Float16*       kh    = (_Float16*)(ws + 8388608);          //  8.39 MB
    _Float16*       vh    = (_Float16*)(ws + 16777216);         //  8.39 MB
    unsigned short* xt    = (unsigned short*)(ws + 25165824);   // 16.78 MB
    unsigned short* Ap    = (unsigned short*)(ws + 41943040);   //  1.18 MB
    float*          biasC = (float*)(ws + 43122688);            //  3 KB

    prep_kernel<<<dim3(1792), 256, 0, stream>>>(x, wq, bq, wk, bk, wv, bv, xt, Ap, biasC);
    qkv_mfma_kernel<<<dim3(768), 256, 0, stream>>>(Ap, xt, biasC, qh, kh, vh);
    loc_attn_kernel<<<dim3(1024), 256, 0, stream>>>(qh, kh, vh, out);
}

// Round 7
// 35.926 us; speedup vs baseline: 7.4090x; 1.4253x over previous
//
#include <hip/hip_runtime.h>
#include <cstddef>
#include <cstdint>

#define BDIM 4
#define HH   64
#define WW   64
#define NG   4
#define GD   64
#define HWSZ 4096
#define NTOT 16384          // BDIM*HWSZ
#define XTC  256            // xt row: fp16 x^T, 256 channels

typedef __attribute__((ext_vector_type(4))) float f32x4;
typedef _Float16 f16x4_t __attribute__((ext_vector_type(4)));
typedef _Float16 f16x8_t __attribute__((ext_vector_type(8)));

__device__ __forceinline__ void lds_load16(const void* g, void* l) {
    __builtin_amdgcn_global_load_lds(
        (const __attribute__((address_space(1))) unsigned int*)g,
        (__attribute__((address_space(3))) unsigned int*)l, 16, 0, 0);
}

// ---------- fused prep: blocks 0..1023 transpose x -> fp16, 1024..1791 W -> fp16 + bias ----------
__global__ __launch_bounds__(256) void prep_kernel(
    const float* __restrict__ x,
    const float* __restrict__ wq, const float* __restrict__ bq,
    const float* __restrict__ wk, const float* __restrict__ bk,
    const float* __restrict__ wv, const float* __restrict__ bv,
    _Float16* __restrict__ xt, _Float16* __restrict__ Ap,
    float* __restrict__ biasC)
{
    __shared__ float tile[64][65];
    const int t = threadIdx.x;
    const int bx = blockIdx.x;

    if (bx < 1024) {
        const int n0 = (bx & 63) * 64;
        const int c0 = ((bx >> 6) & 3) * 64;
        const int b  = bx >> 8;

        const int tr = t >> 4, tc = (t & 15) * 4;
        #pragma unroll
        for (int i = 0; i < 4; ++i) {
            const int row = tr + i * 16;
            const float4 v = *(const float4*)&x[(size_t)(b * 256 + c0 + row) * HWSZ + n0 + tc];
            tile[row][tc + 0] = v.x; tile[row][tc + 1] = v.y;
            tile[row][tc + 2] = v.z; tile[row][tc + 3] = v.w;
        }
        __syncthreads();

        const int nr = t >> 2, cc = (t & 3) * 16;
        f16x8_t h0, h1;
        #pragma unroll
        for (int j = 0; j < 8; ++j) h0[j] = (_Float16)tile[cc + j][nr];
        #pragma unroll
        for (int j = 0; j < 8; ++j) h1[j] = (_Float16)tile[cc + 8 + j][nr];
        const size_t base = (size_t)(b * HWSZ + n0 + nr) * XTC + c0 + cc;
        *(f16x8_t*)&xt[base]     = h0;
        *(f16x8_t*)&xt[base + 8] = h1;
    } else {
        const int m  = bx - 1024;          // 0..767 (q:0-255, k:256-511, v:512-767)
        const int mm = m & 255;
        const float* w = (m < 256) ? wq : (m < 512) ? wk : wv;
        Ap[(size_t)m * XTC + t] = (_Float16)w[(size_t)mm * 256 + t];
        if (t == 0) biasC[m] = (m < 256) ? bq[mm] : (m < 512) ? bk[mm] : bv[mm];
    }
}

// ---------- QKV GEMM: [768 x 256] * [256 x 16384] fp16 MFMA, BK=32 ----------
// 128x128 tile, 4 waves, global_load_lds w16, 8 K-steps. Blocked fp16 outputs.
__global__ __launch_bounds__(256) void qkv_mfma_kernel(
    const _Float16* __restrict__ Ap, const _Float16* __restrict__ xt,
    const float* __restrict__ biasC, _Float16* __restrict__ qh,
    _Float16* __restrict__ kh, _Float16* __restrict__ vh)
{
    __shared__ _Float16 As[128 * 32];   // 8 KB
    __shared__ _Float16 Bs[128 * 32];   // 8 KB

    const int t  = threadIdx.x;
    const int bx = blockIdx.x;
    const int u  = (bx & 7) * 96 + (bx >> 3);   // XCD-chunked (768 = 8*96)
    const int mt = u % 6;
    const int nt = u / 6;                       // 0..127

    const int l     = t & 63;
    const int wid   = t >> 6;
    const int wm    = wid >> 1, wn = wid & 1;
    const int lrow  = l & 15;
    const int lk    = (l >> 4) * 8;
    const int lrow4 = (l >> 4) * 4;

    f32x4 acc[4][4];
    #pragma unroll
    for (int mi = 0; mi < 4; ++mi) {
        const f32x4 bb = *(const f32x4*)&biasC[mt * 128 + wm * 64 + mi * 16 + lrow4];
        #pragma unroll
        for (int ni = 0; ni < 4; ++ni) acc[mi][ni] = bb;
    }

    // staging: 8KB per operand per step -> 2 issues of 16B per thread
    const int e  = t * 8;            // fp16 elems within a 4KB half (64 rows x 32k)
    const int r0 = e >> 5;           // row 0..63
    const int kc = e & 31;
    const _Float16* agp0 = Ap + (size_t)(mt * 128 + r0) * XTC + kc;
    const _Float16* agp1 = Ap + (size_t)(mt * 128 + 64 + r0) * XTC + kc;
    const _Float16* bgp0 = xt + (size_t)(nt * 128 + r0) * XTC + kc;
    const _Float16* bgp1 = xt + (size_t)(nt * 128 + 64 + r0) * XTC + kc;

    for (int kt = 0; kt < 8; ++kt) {
        const int ka = kt * 32;
        lds_load16(agp0 + ka, As + t * 8);
        lds_load16(agp1 + ka, As + 2048 + t * 8);
        lds_load16(bgp0 + ka, Bs + t * 8);
        lds_load16(bgp1 + ka, Bs + 2048 + t * 8);
        __syncthreads();

        f16x8_t a[4], bf[4];
        #pragma unroll
        for (int mi = 0; mi < 4; ++mi)
            a[mi] = *(const f16x8_t*)&As[(wm * 64 + mi * 16 + lrow) * 32 + lk];
        #pragma unroll
        for (int ni = 0; ni < 4; ++ni)
            bf[ni] = *(const f16x8_t*)&Bs[(wn * 64 + ni * 16 + lrow) * 32 + lk];
        #pragma unroll
        for (int mi = 0; mi < 4; ++mi)
            #pragma unroll
            for (int ni = 0; ni < 4; ++ni)
                acc[mi][ni] = __builtin_amdgcn_mfma_f32_16x16x32_f16(
                    a[mi], bf[ni], acc[mi][ni], 0, 0, 0);
        __syncthreads();
    }

    // epilogue: D row (m) = (l>>4)*4+reg, col (n) = l&15 — blocked fp16 stores
    #pragma unroll
    for (int ni = 0; ni < 4; ++ni) {
        const size_t ng = (size_t)(nt * 128 + wn * 64 + ni * 16 + lrow);
        #pragma unroll
        for (int mi = 0; mi < 4; ++mi) {
            f16x4_t hv;
            #pragma unroll
            for (int j = 0; j < 4; ++j) hv[j] = (_Float16)acc[mi][ni][j];
            const int c8 = wm * 4 + mi;                  // 0..7 within this mt
            if (mt < 2)
                *(f16x4_t*)&qh[((size_t)(mt * 8 + c8) * NTOT + ng) * 16 + lrow4] = hv;
            else if (mt < 4)
                *(f16x4_t*)&kh[((size_t)((mt - 2) * 8 + c8) * NTOT + ng) * 16 + lrow4] = hv;
            else
                *(f16x4_t*)&vh[((size_t)((mt - 4) * 8 + c8) * NTOT + ng) * 16 + lrow4] = hv;
        }
    }
}

// ---------- local grouped attention: q,k,v fp16 blocked; fp32 math ----------
__global__ __launch_bounds__(256) void loc_attn_kernel(
    const _Float16* __restrict__ qh, const _Float16* __restrict__ kh,
    const _Float16* __restrict__ vh, float* __restrict__ out)
{
    const int t   = threadIdx.x;
    const int bx0 = blockIdx.x;
    const int bx  = (bx0 & 7) * 128 + (bx0 >> 3);
    const int h = bx & 63;
    const int g = (bx >> 6) & 3;
    const int b = bx >> 8;

    const int wl  = t & 15;
    const int c   = (t >> 4) & 3;
    const int wid = t >> 6;
    const int w   = wid * 16 + wl;

    const int ck = g * 4 + c;                    // chunk index 0..15
    const size_t n = (size_t)b * HWSZ + h * 64 + w;

    float qf[16];
    {
        const _Float16* qp = &qh[((size_t)ck * NTOT + n) * 16];
        const f16x8_t q0 = *(const f16x8_t*)qp;
        const f16x8_t q1 = *(const f16x8_t*)(qp + 8);
        #pragma unroll
        for (int j = 0; j < 8; ++j) { qf[j] = (float)q0[j]; qf[8 + j] = (float)q1[j]; }
    }

    float logit[9];
    #pragma unroll
    for (int p = 0; p < 9; ++p) {
        const int dh = p / 3 - 1, dw = p % 3 - 1;
        const int hh = h + dh, ww2 = w + dw;
        float part = 0.f;
        if (hh >= 0 && hh < HH && ww2 >= 0 && ww2 < WW) {
            const size_t nn = (size_t)b * HWSZ + hh * 64 + ww2;
            const _Float16* kp = &kh[((size_t)ck * NTOT + nn) * 16];
            const f16x8_t k0 = *(const f16x8_t*)kp;
            const f16x8_t k1 = *(const f16x8_t*)(kp + 8);
            #pragma unroll
            for (int j = 0; j < 8; ++j)
                part += qf[j] * (float)k0[j] + qf[8 + j] * (float)k1[j];
        }
        part += __shfl_xor(part, 16, 64);
        part += __shfl_xor(part, 32, 64);
        logit[p] = part;
    }

    float mx = logit[0];
    #pragma unroll
    for (int p = 1; p < 9; ++p) mx = fmaxf(mx, logit[p]);
    float a[9];
    float s = 0.f;
    #pragma unroll
    for (int p = 0; p < 9; ++p) { a[p] = __expf(logit[p] - mx); s += a[p]; }
    const float inv = 1.f / s;
    #pragma unroll
    for (int p = 0; p < 9; ++p) a[p] *= inv;

    float acc[16];
    #pragma unroll
    for (int dd = 0; dd < 16; ++dd) acc[dd] = 0.f;
    #pragma unroll
    for (int p = 0; p < 9; ++p) {
        const int dh = p / 3 - 1, dw = p % 3 - 1;
        const int hh = h + dh, ww2 = w + dw;
        if (hh < 0 || hh >= HH || ww2 < 0 || ww2 >= WW) continue;
        const size_t nn = (size_t)b * HWSZ + hh * 64 + ww2;
        const _Float16* vp = &vh[((size_t)ck * NTOT + nn) * 16];
        const f16x8_t v0 = *(const f16x8_t*)vp;
        const f16x8_t v1 = *(const f16x8_t*)(vp + 8);
        const float ap = a[p];
        #pragma unroll
        for (int j = 0; j < 8; ++j) {
            acc[j]     += ap * (float)v0[j];
            acc[8 + j] += ap * (float)v1[j];
        }
    }

    const int obase = b * 256 + g * 64 + c * 16;
    const int off = h * 64 + w;
    #pragma unroll
    for (int dd = 0; dd < 16; ++dd)
        out[(size_t)(obase + dd) * HWSZ + off] = acc[dd];
}

extern "C" void kernel_launch(void* const* d_in, const int* in_sizes, int n_in,
                              void* d_out, int out_size, void* d_ws, size_t ws_size,
                              hipStream_t stream) {
    const float* x  = (const float*)d_in[0];
    const float* wq = (const float*)d_in[1];
    const float* bq = (const float*)d_in[2];
    const float* wk = (const float*)d_in[3];
    const float* bk = (const float*)d_in[4];
    const float* wv = (const float*)d_in[5];
    const float* bv = (const float*)d_in[6];
    float* out = (float*)d_out;

    char* ws = (char*)d_ws;
    _Float16* qh    = (_Float16*)ws;                      //  8.39 MB
    _Float16* kh    = (_Float16*)(ws + 8388608);          //  8.39 MB
    _Float16* vh    = (_Float16*)(ws + 16777216);         //  8.39 MB
    _Float16* xt    = (_Float16*)(ws + 25165824);         //  8.39 MB
    _Float16* Ap    = (_Float16*)(ws + 33554432);         //  0.39 MB
    float*    biasC = (float*)(ws + 33947648);            //  3 KB

    prep_kernel<<<dim3(1792), 256, 0, stream>>>(x, wq, bq, wk, bk, wv, bv, xt, Ap, biasC);
    qkv_mfma_kernel<<<dim3(768), 256, 0, stream>>>(Ap, xt, biasC, qh, kh, vh);
    loc_attn_kernel<<<dim3(1024), 256, 0, stream>>>(qh, kh, vh, out);
}